// Round 11
// baseline (130.638 us; speedup 1.0000x reference)
//
#include <hip/hip_runtime.h>

// Composite-filter formulation:
//   out[o] = sum_{k=0..54} Cp[r][k] * x[n0 - k],
//     r = (2o+32) % 3, n0 = (2o+32-r)/3,
//     Cp[p][k] = C[p+3k], C[j] = sum_m b[m]*h[j-2m]
//
// R7:  direct-global windows: 46us, VALUBusy 22%.
// R8 FAILED: window reg double-buffer, VGPR 128, occupancy halved.
// R9:  LDS tile + XOR float4-slot swizzle slot(c)=c^((c>>3)&7). <42.6us.
// R10 FAILED perf: LDS coeff table + path merge (VGPR 144). Boundary-fold OK.
// R11: prep merge (3 dispatches -> 2). 117 -> 108.9.
// R12 FAILED: opaque-VGPR coeff idx + occupancy cap -> scratch spills.
//   Lesson: WRITE_SIZE explosion = spill detector.
// R13: single up-front ds burst: neutral. lgkmcnt-conflation REFUTED.
// R14: wave-autonomous staging, no __syncthreads. 107.4.
// R15: coeffs in 3 lane-resident VGPRs + readlane. VGPR 32, VALUBusy 38%,
//   dur UNCHANGED -> coeff-fetch REFUTED; extra issue absorbed free.
// R16: 2-tile cross-tile pipeline: passed, neutral. Convoy REFUTED.
// R17 FAILED correctness (absmax 5.37): bundled 3 novel constructs
//   (bpermute build / negative-shift UB / reg-set reuse WAR); not isolated.
//   Lesson: one novel construct per round.
// R18: single dispatch, zero workspace, ONLY passing-precedent parts:
//   R16 main path + R15 readlane coeffs + R14 staging + R10 boundary fold.
//   New element kept minimal: per-lane coeff build = verbatim prep_k inner
//   loop (ascending m, same guards -> bit-identical), b[m] via s_load,
//   h[hi] via L1-hot global loads. No bpermute, no shifts, no reg reuse.

#define TPB 256
#define RPT 12                    // outputs per thread per tile
#define OTILE (TPB * RPT)         // 3072 outputs per tile
#define WREG 144                  // float4 slots per wave region (144%8==0)
#define NTAPS 55

#define SLOT(c) ((c) ^ (((c) >> 3) & 7))

// Coefficient fetch: flat index i (compile-time constant) -> value held in
// lane (i&63) of table reg (i>>6). readlane result is wave-uniform (SGPR).
__device__ __forceinline__ float co(const int i, const int c0,
                                    const int c1, const int c2) {
    const int ln = i & 63;
    const int v = (i < 64)  ? __builtin_amdgcn_readlane(c0, ln)
                : (i < 128) ? __builtin_amdgcn_readlane(c1, ln)
                            : __builtin_amdgcn_readlane(c2, ln);
    return __int_as_float(v);
}

// Group g covers taps k=4g..4g+3 for 12 outputs d=0..11.
// delta_d = {0,1,2,2,3,4,4,5,6,6,7,8}, phase r_d = (2+2d)%3 -> q2/q1/q0 cycle.
// Flat coeff idx: q0 = 4g+j, q1 = 56+4g+j, q2 = 112+4g+j.
#define GRP12(g, A, B, C, D) {                                          \
    const float q2x = co(112 + 4*(g), cc0, cc1, cc2);                   \
    const float q2y = co(113 + 4*(g), cc0, cc1, cc2);                   \
    const float q2z = co(114 + 4*(g), cc0, cc1, cc2);                   \
    const float q2w = co(115 + 4*(g), cc0, cc1, cc2);                   \
    const float q1x = co( 56 + 4*(g), cc0, cc1, cc2);                   \
    const float q1y = co( 57 + 4*(g), cc0, cc1, cc2);                   \
    const float q1z = co( 58 + 4*(g), cc0, cc1, cc2);                   \
    const float q1w = co( 59 + 4*(g), cc0, cc1, cc2);                   \
    const float q0x = co(      4*(g), cc0, cc1, cc2);                   \
    const float q0y = co(  1 + 4*(g), cc0, cc1, cc2);                   \
    const float q0z = co(  2 + 4*(g), cc0, cc1, cc2);                   \
    const float q0w = co(  3 + 4*(g), cc0, cc1, cc2);                   \
    /* j=0 */                                                           \
    a0  += q2x * C.z;  a1  += q1x * C.w;  a2  += q0x * B.x;             \
    a3  += q2x * B.x;  a4  += q1x * B.y;  a5  += q0x * B.z;             \
    a6  += q2x * B.z;  a7  += q1x * B.w;  a8  += q0x * A.x;             \
    a9  += q2x * A.x;  a10 += q1x * A.y;  a11 += q0x * A.z;             \
    /* j=1 */                                                           \
    a0  += q2y * C.y;  a1  += q1y * C.z;  a2  += q0y * C.w;             \
    a3  += q2y * C.w;  a4  += q1y * B.x;  a5  += q0y * B.y;             \
    a6  += q2y * B.y;  a7  += q1y * B.z;  a8  += q0y * B.w;             \
    a9  += q2y * B.w;  a10 += q1y * A.x;  a11 += q0y * A.y;             \
    /* j=2 */                                                           \
    a0  += q2z * C.x;  a1  += q1z * C.y;  a2  += q0z * C.z;             \
    a3  += q2z * C.z;  a4  += q1z * C.w;  a5  += q0z * B.x;             \
    a6  += q2z * B.x;  a7  += q1z * B.y;  a8  += q0z * B.z;             \
    a9  += q2z * B.z;  a10 += q1z * B.w;  a11 += q0z * A.x;             \
    /* j=3 */                                                           \
    a0  += q2w * D.w;  a1  += q1w * C.x;  a2  += q0w * C.y;             \
    a3  += q2w * C.y;  a4  += q1w * C.z;  a5  += q0w * C.w;             \
    a6  += q2w * C.w;  a7  += q1w * B.x;  a8  += q0w * B.y;             \
    a9  += q2w * B.y;  a10 += q1w * B.z;  a11 += q0w * B.w; }

// Tail group: j=0..2 only (k = 52,53,54).
#define GRP12T(g, A, B, C) {                                            \
    const float q2x = co(112 + 4*(g), cc0, cc1, cc2);                   \
    const float q2y = co(113 + 4*(g), cc0, cc1, cc2);                   \
    const float q2z = co(114 + 4*(g), cc0, cc1, cc2);                   \
    const float q1x = co( 56 + 4*(g), cc0, cc1, cc2);                   \
    const float q1y = co( 57 + 4*(g), cc0, cc1, cc2);                   \
    const float q1z = co( 58 + 4*(g), cc0, cc1, cc2);                   \
    const float q0x = co(      4*(g), cc0, cc1, cc2);                   \
    const float q0y = co(  1 + 4*(g), cc0, cc1, cc2);                   \
    const float q0z = co(  2 + 4*(g), cc0, cc1, cc2);                   \
    a0  += q2x * C.z;  a1  += q1x * C.w;  a2  += q0x * B.x;             \
    a3  += q2x * B.x;  a4  += q1x * B.y;  a5  += q0x * B.z;             \
    a6  += q2x * B.z;  a7  += q1x * B.w;  a8  += q0x * A.x;             \
    a9  += q2x * A.x;  a10 += q1x * A.y;  a11 += q0x * A.z;             \
    a0  += q2y * C.y;  a1  += q1y * C.z;  a2  += q0y * C.w;             \
    a3  += q2y * C.w;  a4  += q1y * B.x;  a5  += q0y * B.y;             \
    a6  += q2y * B.y;  a7  += q1y * B.z;  a8  += q0y * B.w;             \
    a9  += q2y * B.w;  a10 += q1y * A.x;  a11 += q0y * A.y;             \
    a0  += q2z * C.x;  a1  += q1z * C.y;  a2  += q0z * C.z;             \
    a3  += q2z * C.z;  a4  += q1z * C.w;  a5  += q0z * B.x;             \
    a6  += q2z * B.x;  a7  += q1z * B.y;  a8  += q0z * B.z;             \
    a9  += q2z * B.z;  a10 += q1z * B.w;  a11 += q0z * A.x; }

// Guarded staging for boundary tiles (first/last main block only).
#define EDGE_STAGE(NT) {                                                \
    const int fb0 = (NT) + 512 * w;                                     \
    _Pragma("unroll")                                                   \
    for (int s = 0; s < 3; ++s) {                                       \
        const int c = l + 64 * s;                                       \
        if (c > 141) break;                                             \
        const int fb = fb0 + 4 * c;                                     \
        float4 v;                                                       \
        v.x = (fb + 0 >= 0 && fb + 0 < n_in) ? x[fb + 0] : 0.0f;        \
        v.y = (fb + 1 >= 0 && fb + 1 < n_in) ? x[fb + 1] : 0.0f;        \
        v.z = (fb + 2 >= 0 && fb + 2 < n_in) ? x[fb + 2] : 0.0f;        \
        v.w = (fb + 3 >= 0 && fb + 3 < n_in) ? x[fb + 3] : 0.0f;        \
        xs4[wreg + SLOT(c)] = v;                                        \
    } }

#define XS(j) xs4[wreg + SLOT(2 * l + (j))]

// Full per-tile compute: 6-reg rotating window + 12-output store.
#define TILE_COMPUTE(OB) {                                              \
    float a0 = 0.f, a1 = 0.f, a2 = 0.f, a3  = 0.f, a4  = 0.f, a5 = 0.f;\
    float a6 = 0.f, a7 = 0.f, a8 = 0.f, a9  = 0.f, a10 = 0.f, a11 = 0.f;\
    {                                                                   \
        float4 r0 = XS(15), r1 = XS(14), r2 = XS(13),                   \
               r3 = XS(12), r4 = XS(11), r5 = XS(10);                   \
        GRP12( 0, r0, r1, r2, r3);  r0 = XS(9);                         \
        GRP12( 1, r1, r2, r3, r4);  r1 = XS(8);                         \
        GRP12( 2, r2, r3, r4, r5);  r2 = XS(7);                         \
        GRP12( 3, r3, r4, r5, r0);  r3 = XS(6);                         \
        GRP12( 4, r4, r5, r0, r1);  r4 = XS(5);                         \
        GRP12( 5, r5, r0, r1, r2);  r5 = XS(4);                         \
        GRP12( 6, r0, r1, r2, r3);  r0 = XS(3);                         \
        GRP12( 7, r1, r2, r3, r4);  r1 = XS(2);                         \
        GRP12( 8, r2, r3, r4, r5);  r2 = XS(1);                         \
        GRP12( 9, r3, r4, r5, r0);  r3 = XS(0);                         \
        GRP12(10, r4, r5, r0, r1);                                      \
        GRP12(11, r5, r0, r1, r2);                                      \
        GRP12(12, r0, r1, r2, r3);                                      \
        GRP12T(13, r1, r2, r3);                                         \
    }                                                                   \
    const int ob_ = (OB);                                               \
    if (ob_ >= 50 && ob_ + 11 < n_out) {                                \
        float4* o4 = (float4*)(out + ob_);   /* 16B aligned */          \
        o4[0] = make_float4(a0, a1, a2,  a3);                           \
        o4[1] = make_float4(a4, a5, a6,  a7);                           \
        o4[2] = make_float4(a8, a9, a10, a11);                          \
    } else {                                                            \
        const float accs[RPT] = {a0,a1,a2,a3,a4,a5,a6,a7,a8,a9,a10,a11};\
        _Pragma("unroll")                                               \
        for (int d = 0; d < RPT; ++d) {                                 \
            const int o = ob_ + d;                                      \
            if (o >= 50 && o < n_out) out[o] = accs[d];                 \
        }                                                               \
    } }

__global__ __launch_bounds__(TPB) void fused_all(
    const float* __restrict__ x, const float* __restrict__ h,
    const float* __restrict__ b, float* __restrict__ out,
    int n_in, int n_out, int out_size, int nmain)
{
    __shared__ float4 xs4[4 * WREG];   // 9216 B; per-wave regions (main path)

    const int tid = threadIdx.x;
    const int bid = blockIdx.x;

    // ---------------- boundary blocks (grid tail; R10-proven fold) ---------
    if (bid >= nmain) {
        float* const h_s = (float*)xs4;          // 63
        float* const b_s = (float*)xs4 + 64;     // 51
        float* const x_s = (float*)xs4 + 128;    // 64
        float* const u_s = (float*)xs4 + 192;    // 50

        if (tid < 63) h_s[tid] = h[tid];
        if (tid < 51) b_s[tid] = b[tid];

        if (bid == nmain) {                      // head: o in [0,50)
            if (tid < 44) x_s[tid] = (tid < n_in) ? x[tid] : 0.0f;
            __syncthreads();
            if (tid < 50) {
                const int s  = 2 * tid + 32;
                const int p0 = s % 3;
                const int q  = s / 3;
                float u = 0.0f;
                #pragma unroll
                for (int i = 0; i <= 20; ++i) {
                    const int xi = q - i;
                    u += h_s[p0 + 3 * i] * ((xi >= 0) ? x_s[xi] : 0.0f);
                }
                u_s[tid] = u;
            }
            __syncthreads();
            if (tid < 50) {
                float acc = 0.0f;
                for (int t = 0; t <= tid; ++t) acc += b_s[tid - t] * u_s[t];
                out[tid] = acc;
            }
        } else {                                 // tail: o in [n_out, out_size)
            const int t0   = n_out - 50;
            const int qmin = (2 * t0 + 32) / 3;
            const int xb   = qmin - 20;
            if (tid < 64) {
                const int xi = xb + tid;
                x_s[tid] = (xi >= 0 && xi < n_in) ? x[xi] : 0.0f;
            }
            __syncthreads();
            if (tid < 50) {
                const int t  = t0 + tid;
                const int s  = 2 * t + 32;
                const int p0 = s % 3;
                const int q  = s / 3;
                const int base = q - xb;
                float u = 0.0f;
                #pragma unroll
                for (int i = 0; i <= 20; ++i)
                    u += h_s[p0 + 3 * i] * x_s[base - i];
                u_s[tid] = u;
            }
            __syncthreads();
            const int n_tail = out_size - n_out; // 96
            if (tid < n_tail) {
                float acc = 0.0f;
                for (int j = tid; j <= 49; ++j) acc += b_s[tid + 50 - j] * u_s[j];
                out[n_out + tid] = acc;
            }
        }
        return;
    }

    // ---------------- main blocks: R16's 2-tile pipeline -------------------
    const int w   = tid >> 6;                    // wave id 0..3
    const int l   = tid & 63;                    // lane
    const int wreg = w * WREG;
    const int o0  = bid * (2 * OTILE);           // 6144 outputs per block
    const int ntA = 4096 * bid - 44;             // tile A x-base (mult of 4)
    const int ntB = ntA + 2048;                  // tile B x-base

    const bool intA = (ntA >= 0) && (ntA + 2104 <= n_in);
    const bool intB = (ntB >= 0) && (ntB + 2104 <= n_in);

    // ---- issue both tiles' global loads up front (R16, passed) ----
    float4 ga0, ga1, ga2, gb0, gb1, gb2;
    if (intA) {
        const float4* gw = (const float4*)(x + ntA) + 128 * w;
        ga0 = gw[l];
        ga1 = gw[l + 64];
        if (l < 14) ga2 = gw[l + 128];
    }
    if (intB) {
        const float4* gw = (const float4*)(x + ntB) + 128 * w;
        gb0 = gw[l];
        gb1 = gw[l + 64];
        if (l < 14) gb2 = gw[l + 128];
    }
    __builtin_amdgcn_sched_barrier(0);           // pin prefetch issue point

    // ---- per-lane coefficient build: verbatim prep_k math -----------------
    // Lane l builds cp[l] (cc0), cp[64+l] (cc1), cp[128+l] (cc2; l>=40
    // computes cp[128], never read). Same ascending-m order and guards as
    // the old prep kernel -> bit-identical values. b[m] is wave-uniform
    // (s_load); h[hi] is per-lane (L1-hot 252B region).
    int cc0, cc1, cc2;
    {
        const int iA = l;
        const int iB = 64 + l;
        const int iC = (l < 40) ? (128 + l) : 128;
        const int pA = iA / 56, kA = iA - pA * 56;
        const int pB = iB / 56, kB = iB - pB * 56;
        const int pC = iC / 56, kC = iC - pC * 56;
        int jA = pA + 3 * kA;
        int jB = pB + 3 * kB;
        int jC = pC + 3 * kC;
        float aA = 0.0f, aB = 0.0f, aC = 0.0f;
        for (int m = 0; m <= 50; ++m) {
            const float bm = b[m];
            if (jA >= 0 && jA <= 62) aA += bm * h[jA];
            if (jB >= 0 && jB <= 62) aB += bm * h[jB];
            if (jC >= 0 && jC <= 62) aC += bm * h[jC];
            jA -= 2; jB -= 2; jC -= 2;
        }
        cc0 = __float_as_int((kA < NTAPS) ? aA : 0.0f);
        cc1 = __float_as_int((kB < NTAPS) ? aB : 0.0f);
        cc2 = __float_as_int((kC < NTAPS) ? aC : 0.0f);
    }
    __builtin_amdgcn_sched_barrier(0);

    // ---- stage + compute tile A ----
    if (intA) {
        xs4[wreg + SLOT(l)]      = ga0;          // vmcnt waits only A-loads
        xs4[wreg + SLOT(l + 64)] = ga1;
        if (l < 14) xs4[wreg + SLOT(l + 128)] = ga2;
    } else {
        EDGE_STAGE(ntA);
    }
    TILE_COMPUTE(o0 + RPT * tid);

    // ---- stage + compute tile B ----
    // DS is in-order per wave: these writes execute after tile A's last
    // ds_read; gb* landed long ago. No barrier (R16-proven).
    if (intB) {
        xs4[wreg + SLOT(l)]      = gb0;
        xs4[wreg + SLOT(l + 64)] = gb1;
        if (l < 14) xs4[wreg + SLOT(l + 128)] = gb2;
    } else {
        EDGE_STAGE(ntB);
    }
    TILE_COMPUTE(o0 + OTILE + RPT * tid);
}

extern "C" void kernel_launch(void* const* d_in, const int* in_sizes, int n_in_arrs,
                              void* d_out, int out_size, void* d_ws, size_t ws_size,
                              hipStream_t stream) {
    const float* x = (const float*)d_in[0];
    const float* h = (const float*)d_in[1];
    const float* b = (const float*)d_in[2];
    float* out = (float*)d_out;
    (void)d_ws; (void)ws_size;                        // workspace unused

    const int n_in  = in_sizes[0];                    // 8388608
    const int n_out = (int)((long long)n_in * 3 / 2); // 12582912

    const int ntiles = (n_out + OTILE - 1) / OTILE;   // 4096
    const int nmain  = (ntiles + 1) / 2;              // 2048 (2 tiles/block)
    fused_all<<<nmain + 2, TPB, 0, stream>>>(x, h, b, out,
                                             n_in, n_out, out_size, nmain);
}

// Round 12
// 106.817 us; speedup vs baseline: 1.2230x; 1.2230x over previous
//
#include <hip/hip_runtime.h>

// Composite-filter formulation:
//   out[o] = sum_{k=0..54} Cp[r][k] * x[n0 - k],
//     r = (2o+32) % 3, n0 = (2o+32-r)/3,
//     Cp[p][k] = C[p+3k], C[j] = sum_m b[m]*h[j-2m]
//
// FINAL CONFIG (R15, best measured: total 106.4us):
//   prep_k (3 blocks: coeff build + head/tail boundary) -> fused_fast
//   (4096 blocks, wave-autonomous swizzled LDS staging, lane-resident
//   coeff table + readlane, 6-reg rotating window).
//
// Session journal:
// R7:  direct-global windows: 46us, VALUBusy 22%.
// R8 FAILED: window reg double-buffer, VGPR 128, occupancy halved, 77us.
//   Lesson: latency hiding here comes from TLP (8 waves/SIMD at low VGPR).
// R9:  LDS tile + XOR float4-slot swizzle slot(c)=c^((c>>3)&7). <42.6us.
// R10 FAILED: LDS coeff table (uniform ds_read_b128 not free) + path merge.
// R11: prep merge (3 dispatches -> 2). 117 -> 108.9.
// R12 FAILED: opaque-VGPR coeff idx + occupancy cap -> scratch spills (946us).
//   Lesson: WRITE_SIZE explosion = spill detector.
// R13: single up-front ds burst: neutral. lgkmcnt-conflation REFUTED.
// R14: wave-autonomous staging, no __syncthreads. 107.4.
// R15: coeffs in 3 lane-resident VGPRs + readlane. VGPR 32, VALUBusy 38%,
//   fused wall UNCHANGED -> coeff-fetch REFUTED; extra parallel issue is
//   absorbed free. 106.4 (BEST).
// R16: 2-tile cross-tile pipeline: neutral. Convoy theory REFUTED.
// R17 FAILED correctness: 3 novel constructs bundled. Lesson: one per round.
// R18 regressed (130.6): in-kernel per-block coeff build = serial-prefix
//   dependency chain on every block's critical path (+20us). Lesson: issue
//   slack absorbs PARALLEL work, never SERIAL-PREFIX work.
// Conclusion: fused ~43us is invariant to scheduling/source/sync/dispatch
//   structure across 7 orthogonal interventions; remaining bench time is
//   harness fills (~51us) + prep + launch overhead. Practical floor.

#define TPB 256
#define RPT 12                    // outputs per thread
#define OTILE (TPB * RPT)         // 3072 outputs per block
#define WREG 144                  // float4 slots per wave region (144%8==0)
#define NTAPS 55
#define CPSTRIDE 56               // phase-major coeff stride (zero-padded)

#define SLOT(c) ((c) ^ (((c) >> 3) & 7))

// One dispatch, 3 independent blocks:
//   block 0: build cp[3*56] composite coefficients
//   block 1: head boundary (o in [0,50))
//   block 2: tail boundary (o in [n_out, out_size))
__global__ __launch_bounds__(TPB) void prep_k(
    const float* __restrict__ x, const float* __restrict__ h,
    const float* __restrict__ b, float* __restrict__ cp,
    float* __restrict__ out, int n_in, int n_out, int out_size)
{
    __shared__ float h_s[63];
    __shared__ float b_s[51];
    __shared__ float x_s[64];
    __shared__ float u_s[50];

    const int tid = threadIdx.x;
    if (tid < 63) h_s[tid] = h[tid];
    if (tid < 51) b_s[tid] = b[tid];

    if (blockIdx.x == 0) {
        __syncthreads();
        for (int idx = tid; idx < 3 * CPSTRIDE; idx += TPB) {
            const int p = idx / CPSTRIDE;
            const int k = idx - p * CPSTRIDE;
            float acc = 0.0f;
            if (k < NTAPS) {
                const int j = p + 3 * k;
                for (int m = 0; m <= 50; ++m) {
                    const int hi = j - 2 * m;
                    if (hi >= 0 && hi <= 62) acc += b_s[m] * h_s[hi];
                }
            }
            cp[idx] = acc;
        }
    } else if (blockIdx.x == 1) {
        if (tid < 44) x_s[tid] = (tid < n_in) ? x[tid] : 0.0f;
        __syncthreads();
        if (tid < 50) {
            const int s  = 2 * tid + 32;
            const int p0 = s % 3;
            const int q  = s / 3;
            float u = 0.0f;
            #pragma unroll
            for (int i = 0; i <= 20; ++i) {
                const int xi = q - i;
                u += h_s[p0 + 3 * i] * ((xi >= 0) ? x_s[xi] : 0.0f);
            }
            u_s[tid] = u;
        }
        __syncthreads();
        if (tid < 50) {
            float acc = 0.0f;
            for (int t = 0; t <= tid; ++t) acc += b_s[tid - t] * u_s[t];
            out[tid] = acc;
        }
    } else {
        const int t0   = n_out - 50;
        const int qmin = (2 * t0 + 32) / 3;
        const int xb   = qmin - 20;
        if (tid < 64) {
            const int xi = xb + tid;
            x_s[tid] = (xi >= 0 && xi < n_in) ? x[xi] : 0.0f;
        }
        __syncthreads();
        if (tid < 50) {
            const int t  = t0 + tid;
            const int s  = 2 * t + 32;
            const int p0 = s % 3;
            const int q  = s / 3;
            const int base = q - xb;
            float u = 0.0f;
            #pragma unroll
            for (int i = 0; i <= 20; ++i)
                u += h_s[p0 + 3 * i] * x_s[base - i];
            u_s[tid] = u;
        }
        __syncthreads();
        const int n_tail = out_size - n_out;   // 96
        if (tid < n_tail) {
            float acc = 0.0f;
            for (int j = tid; j <= 49; ++j) acc += b_s[tid + 50 - j] * u_s[j];
            out[n_out + tid] = acc;
        }
    }
}

// Coefficient fetch: flat index i (compile-time constant) -> value held in
// lane (i&63) of table reg (i>>6). readlane result is wave-uniform (SGPR).
__device__ __forceinline__ float co(const int i, const int c0,
                                    const int c1, const int c2) {
    const int ln = i & 63;
    const int v = (i < 64)  ? __builtin_amdgcn_readlane(c0, ln)
                : (i < 128) ? __builtin_amdgcn_readlane(c1, ln)
                            : __builtin_amdgcn_readlane(c2, ln);
    return __int_as_float(v);
}

// Group g covers taps k=4g..4g+3 for 12 outputs d=0..11.
// delta_d = {0,1,2,2,3,4,4,5,6,6,7,8}, phase r_d = (2+2d)%3 -> q2/q1/q0 cycle.
// Flat coeff idx: q0 = 4g+j, q1 = 56+4g+j, q2 = 112+4g+j.
#define GRP12(g, A, B, C, D) {                                          \
    const float q2x = co(112 + 4*(g), cc0, cc1, cc2);                   \
    const float q2y = co(113 + 4*(g), cc0, cc1, cc2);                   \
    const float q2z = co(114 + 4*(g), cc0, cc1, cc2);                   \
    const float q2w = co(115 + 4*(g), cc0, cc1, cc2);                   \
    const float q1x = co( 56 + 4*(g), cc0, cc1, cc2);                   \
    const float q1y = co( 57 + 4*(g), cc0, cc1, cc2);                   \
    const float q1z = co( 58 + 4*(g), cc0, cc1, cc2);                   \
    const float q1w = co( 59 + 4*(g), cc0, cc1, cc2);                   \
    const float q0x = co(      4*(g), cc0, cc1, cc2);                   \
    const float q0y = co(  1 + 4*(g), cc0, cc1, cc2);                   \
    const float q0z = co(  2 + 4*(g), cc0, cc1, cc2);                   \
    const float q0w = co(  3 + 4*(g), cc0, cc1, cc2);                   \
    /* j=0 */                                                           \
    a0  += q2x * C.z;  a1  += q1x * C.w;  a2  += q0x * B.x;             \
    a3  += q2x * B.x;  a4  += q1x * B.y;  a5  += q0x * B.z;             \
    a6  += q2x * B.z;  a7  += q1x * B.w;  a8  += q0x * A.x;             \
    a9  += q2x * A.x;  a10 += q1x * A.y;  a11 += q0x * A.z;             \
    /* j=1 */                                                           \
    a0  += q2y * C.y;  a1  += q1y * C.z;  a2  += q0y * C.w;             \
    a3  += q2y * C.w;  a4  += q1y * B.x;  a5  += q0y * B.y;             \
    a6  += q2y * B.y;  a7  += q1y * B.z;  a8  += q0y * B.w;             \
    a9  += q2y * B.w;  a10 += q1y * A.x;  a11 += q0y * A.y;             \
    /* j=2 */                                                           \
    a0  += q2z * C.x;  a1  += q1z * C.y;  a2  += q0z * C.z;             \
    a3  += q2z * C.z;  a4  += q1z * C.w;  a5  += q0z * B.x;             \
    a6  += q2z * B.x;  a7  += q1z * B.y;  a8  += q0z * B.z;             \
    a9  += q2z * B.z;  a10 += q1z * B.w;  a11 += q0z * A.x;             \
    /* j=3 */                                                           \
    a0  += q2w * D.w;  a1  += q1w * C.x;  a2  += q0w * C.y;             \
    a3  += q2w * C.y;  a4  += q1w * C.z;  a5  += q0w * C.w;             \
    a6  += q2w * C.w;  a7  += q1w * B.x;  a8  += q0w * B.y;             \
    a9  += q2w * B.y;  a10 += q1w * B.z;  a11 += q0w * B.w; }

// Tail group: j=0..2 only (k = 52,53,54).
#define GRP12T(g, A, B, C) {                                            \
    const float q2x = co(112 + 4*(g), cc0, cc1, cc2);                   \
    const float q2y = co(113 + 4*(g), cc0, cc1, cc2);                   \
    const float q2z = co(114 + 4*(g), cc0, cc1, cc2);                   \
    const float q1x = co( 56 + 4*(g), cc0, cc1, cc2);                   \
    const float q1y = co( 57 + 4*(g), cc0, cc1, cc2);                   \
    const float q1z = co( 58 + 4*(g), cc0, cc1, cc2);                   \
    const float q0x = co(      4*(g), cc0, cc1, cc2);                   \
    const float q0y = co(  1 + 4*(g), cc0, cc1, cc2);                   \
    const float q0z = co(  2 + 4*(g), cc0, cc1, cc2);                   \
    a0  += q2x * C.z;  a1  += q1x * C.w;  a2  += q0x * B.x;             \
    a3  += q2x * B.x;  a4  += q1x * B.y;  a5  += q0x * B.z;             \
    a6  += q2x * B.z;  a7  += q1x * B.w;  a8  += q0x * A.x;             \
    a9  += q2x * A.x;  a10 += q1x * A.y;  a11 += q0x * A.z;             \
    a0  += q2y * C.y;  a1  += q1y * C.z;  a2  += q0y * C.w;             \
    a3  += q2y * C.w;  a4  += q1y * B.x;  a5  += q0y * B.y;             \
    a6  += q2y * B.y;  a7  += q1y * B.z;  a8  += q0y * B.w;             \
    a9  += q2y * B.w;  a10 += q1y * A.x;  a11 += q0y * A.y;             \
    a0  += q2z * C.x;  a1  += q1z * C.y;  a2  += q0z * C.z;             \
    a3  += q2z * C.z;  a4  += q1z * C.w;  a5  += q0z * B.x;             \
    a6  += q2z * B.x;  a7  += q1z * B.y;  a8  += q0z * B.z;             \
    a9  += q2z * B.z;  a10 += q1z * B.w;  a11 += q0z * A.x; }

__global__ __launch_bounds__(TPB) void fused_fast(
    const float* __restrict__ x, const float* __restrict__ cp,
    float* __restrict__ out, int n_in, int n_out)
{
    __shared__ float4 xs4[4 * WREG];   // 9216 B, per-wave swizzled regions

    const int tid = threadIdx.x;
    const int w   = tid >> 6;                    // wave id 0..3
    const int l   = tid & 63;                    // lane
    const int bt  = blockIdx.x;
    const int o0  = bt * OTILE;                  // multiple of 3072
    const int n_tile0 = 2048 * bt - 44;          // tile x-base, multiple of 4
    const int wreg = w * WREG;                   // this wave's LDS region base

    // ---- lane-resident coefficient table: 3 VGPRs cover all 168 floats ----
    // lane l holds cp[l], cp[64+l], cp[128+l] (lanes >=40 of reg2 unused).
    const int cc0 = __float_as_int(cp[l]);
    const int cc1 = __float_as_int(cp[l + 64]);
    const int cc2 = __float_as_int(cp[(l < 40) ? (128 + l) : 128]);

    // ---- wave-autonomous staging: lane l stages local chunks l, l+64,
    //      and (l<14) l+128 of this wave's 142-chunk window [0,141].
    //      NO __syncthreads: compute reads only own-wave region.
    const bool interior = (n_tile0 >= 0) && (n_tile0 + 2104 <= n_in);
    if (interior) {
        const float4* gw = (const float4*)(x + n_tile0) + 128 * w;
        const float4 g0 = gw[l];
        const float4 g1 = gw[l + 64];
        xs4[wreg + SLOT(l)]      = g0;
        xs4[wreg + SLOT(l + 64)] = g1;
        if (l < 14) {
            xs4[wreg + SLOT(l + 128)] = gw[l + 128];
        }
    } else {
        const int fb0 = n_tile0 + 512 * w;       // float base of wave window
        #pragma unroll
        for (int s = 0; s < 3; ++s) {
            const int c = l + 64 * s;            // local chunk
            if (c > 141) break;
            const int fb = fb0 + 4 * c;
            float4 v;
            v.x = (fb + 0 >= 0 && fb + 0 < n_in) ? x[fb + 0] : 0.0f;
            v.y = (fb + 1 >= 0 && fb + 1 < n_in) ? x[fb + 1] : 0.0f;
            v.z = (fb + 2 >= 0 && fb + 2 < n_in) ? x[fb + 2] : 0.0f;
            v.w = (fb + 3 >= 0 && fb + 3 < n_in) ? x[fb + 3] : 0.0f;
            xs4[wreg + SLOT(c)] = v;
        }
    }

    float a0 = 0.f, a1 = 0.f, a2 = 0.f, a3  = 0.f, a4  = 0.f, a5  = 0.f;
    float a6 = 0.f, a7 = 0.f, a8 = 0.f, a9  = 0.f, a10 = 0.f, a11 = 0.f;

    // ---- compute: 6-reg rotating window over local chunks 2l+15 .. 2l ----
#define XS(j) xs4[wreg + SLOT(2 * l + (j))]
    {
        float4 r0 = XS(15), r1 = XS(14), r2 = XS(13),
               r3 = XS(12), r4 = XS(11), r5 = XS(10);
        GRP12( 0, r0, r1, r2, r3);  r0 = XS(9);
        GRP12( 1, r1, r2, r3, r4);  r1 = XS(8);
        GRP12( 2, r2, r3, r4, r5);  r2 = XS(7);
        GRP12( 3, r3, r4, r5, r0);  r3 = XS(6);
        GRP12( 4, r4, r5, r0, r1);  r4 = XS(5);
        GRP12( 5, r5, r0, r1, r2);  r5 = XS(4);
        GRP12( 6, r0, r1, r2, r3);  r0 = XS(3);
        GRP12( 7, r1, r2, r3, r4);  r1 = XS(2);
        GRP12( 8, r2, r3, r4, r5);  r2 = XS(1);
        GRP12( 9, r3, r4, r5, r0);  r3 = XS(0);
        GRP12(10, r4, r5, r0, r1);
        GRP12(11, r5, r0, r1, r2);
        GRP12(12, r0, r1, r2, r3);
        GRP12T(13, r1, r2, r3);
    }
#undef XS

    // ---- store 12 outputs ----
    const int ob = o0 + RPT * tid;               // multiple of 12
    if (ob >= 50 && ob + 11 < n_out) {
        float4* o4 = (float4*)(out + ob);        // 16B aligned (ob % 4 == 0)
        o4[0] = make_float4(a0, a1, a2,  a3);
        o4[1] = make_float4(a4, a5, a6,  a7);
        o4[2] = make_float4(a8, a9, a10, a11);
    } else {
        const float accs[RPT] = {a0, a1, a2, a3, a4, a5, a6, a7, a8, a9, a10, a11};
#pragma unroll
        for (int d = 0; d < RPT; ++d) {
            const int o = ob + d;
            if (o >= 50 && o < n_out) out[o] = accs[d];
        }
    }
}

extern "C" void kernel_launch(void* const* d_in, const int* in_sizes, int n_in_arrs,
                              void* d_out, int out_size, void* d_ws, size_t ws_size,
                              hipStream_t stream) {
    const float* x = (const float*)d_in[0];
    const float* h = (const float*)d_in[1];
    const float* b = (const float*)d_in[2];
    float* out = (float*)d_out;
    float* cp  = (float*)d_ws;                        // 3*56*4 = 672 bytes

    const int n_in  = in_sizes[0];                    // 8388608
    const int n_out = (int)((long long)n_in * 3 / 2); // 12582912

    prep_k<<<3, TPB, 0, stream>>>(x, h, b, cp, out, n_in, n_out, out_size);

    const int nblocks = (n_out + OTILE - 1) / OTILE;  // 4096
    fused_fast<<<nblocks, TPB, 0, stream>>>(x, cp, out, n_in, n_out);
}